// Round 9
// baseline (395.869 us; speedup 1.0000x reference)
//
#include <hip/hip_runtime.h>

// TransR scoring: out[b] = -sum_j | (h_head[b]-h_tail[b]) . P_r[:,j] + e_r[j] |
// B=32768, NFEATS=128, RFEATS=64, NUM_RELS=1000.
//
// Round-9 = round-7 structure (scatter pre-pass, 1000 blocks x 512 thr,
// async P->LDS staging, ONE __syncthreads, per-wave independence; 43 us,
// VGPR 16, 0 conflicts) with the readlane-heavy inner loop replaced by the
// r1/r2-validated (jg,part) fragment loop:
//   per kk: 4x P ds_read_b128 (bank-capacity floor, 0 conflicts measured)
//         + 4x D ds_read_b128 from 36-word-skewed per-wave D-tile
//           (r1-measured conflict-free) + 64 FMA  -> 86% FMA density.
// Next-pass d prefetched to registers before compute, written to LDS after
// (same-wave DS ordering, r4-validated). No inline-asm waitcnt games
// (r8 post-mortem: scratch blowup + 1.1M bank conflicts).

#define NFEATS   128
#define RFEATS   64
#define NUM_RELS 1000
#define STRIDE   128   // bucket slots/rel; cnt~Binom(32768,1e-3) mean 32.8 sd 5.7

#define AS_GLOBAL __attribute__((address_space(1)))
#define AS_SHARED __attribute__((address_space(3)))

__global__ void scatter_kernel(const int* __restrict__ rels,
                               int* __restrict__ cursors,
                               int* __restrict__ bucket, int B) {
    int i = blockIdx.x * blockDim.x + threadIdx.x;
    if (i < B) {
        int r = rels[i];
        int s = atomicAdd(&cursors[r], 1);
        if (s < STRIDE) bucket[(r << 7) + s] = i;
    }
}

__global__ __launch_bounds__(512, 6) void transr_main(
    const float* __restrict__ h_head,
    const float* __restrict__ h_tail,
    const float* __restrict__ rel_emb,
    const float* __restrict__ rel_proj,
    const int*   __restrict__ cursors,
    const int*   __restrict__ bucket,
    float* __restrict__ out)
{
    __shared__ float Plds[NFEATS * RFEATS];   // 32 KB, row-major [n][j]
    __shared__ float Dlds[8][4 * 144];        // 18 KB: per-wave, 4 rows x 144w
    // D word layout (r1-validated): row rr, elem n -> rr*144 + (n>>5)*36 + (n&31)
    // read float4 (p,kk): banks 16rr+4kk+4p -> distinct per p, conflict-free.

    const int r    = blockIdx.x;
    const int tid  = threadIdx.x;              // 512 = 8 waves
    const int w    = tid >> 6;
    const int lane = tid & 63;
    const int jg   = lane & 15;                // column quad: cols 4jg..4jg+3
    const int p    = lane >> 4;                // n-slice [32p, 32p+32)

    int cnt = cursors[r];
    if (cnt > STRIDE) cnt = STRIDE;
    if (cnt == 0) return;                      // uniform; before the barrier

    // ---- issue async P staging first (the long pole the barrier waits on) ----
    const float* Psrc = rel_proj + (size_t)r * (NFEATS * RFEATS);
#if __has_builtin(__builtin_amdgcn_global_load_lds)
#pragma unroll
    for (int it = 0; it < 4; ++it) {
        const int off = (it * 512 + tid) * 4;
        __builtin_amdgcn_global_load_lds((const AS_GLOBAL void*)(Psrc + off),
                                         (AS_SHARED void*)(Plds + off), 16, 0, 0);
    }
#else
#pragma unroll
    for (int it = 0; it < 4; ++it) {
        const int off = (it * 512 + tid) * 4;
        *(float4*)(Plds + off) = *(const float4*)(Psrc + off);
    }
#endif

    const int* buk = bucket + (r << 7);
    float* Dwbase = &Dlds[w][0];
    const int dwr = (lane >> 4) * 36 + 2 * (lane & 15);   // write word offset

    // ---- pass-0 d staging: overlaps P staging latency ----
    int rowid[4];
#pragma unroll
    for (int rr = 0; rr < 4; ++rr) {
        const int li  = (w << 2) + rr;
        const int row = (li < cnt) ? buk[li] : -1;        // uniform -> s_load
        rowid[rr] = row;
        if (row >= 0) {
            const float2 a = *(const float2*)(h_head + (size_t)row * NFEATS + (lane << 1));
            const float2 b = *(const float2*)(h_tail + (size_t)row * NFEATS + (lane << 1));
            float2 d; d.x = a.x - b.x; d.y = a.y - b.y;
            *(float2*)(Dwbase + rr * 144 + dwr) = d;      // wave-private rows
        }
    }

    __syncthreads();   // drains P staging; the only barrier in the kernel

    const float*  Dw = &Dlds[w][p * 36];                  // + rr*144 + kk*4
    const char*   Pb = (const char*)Plds + (p << 13) + (jg << 4); // + kk*1024 + i*256
    const float4  e4 = *(const float4*)(rel_emb + (size_t)r * RFEATS + (jg << 2));

    int base = 0;
    for (;;) {
        const bool have  = (base + (w << 2)) < cnt;       // wave-uniform
        const int  nbase = base + 32;
        const bool nhave = (nbase + (w << 2)) < cnt;

        // ---- prefetch next-pass d into registers (issue-early) ----
        int    nrow[4];
        float2 nd[4];
        if (nhave) {
#pragma unroll
            for (int rr = 0; rr < 4; ++rr) {
                const int li = nbase + (w << 2) + rr;
                nrow[rr] = (li < cnt) ? buk[li] : -1;
                if (nrow[rr] >= 0) {
                    const float2 a = *(const float2*)(h_head + (size_t)nrow[rr] * NFEATS + (lane << 1));
                    const float2 b = *(const float2*)(h_tail + (size_t)nrow[rr] * NFEATS + (lane << 1));
                    nd[rr].x = a.x - b.x;
                    nd[rr].y = a.y - b.y;
                }
            }
        }

        if (have) {
            float acc[4][4];
#pragma unroll
            for (int rr = 0; rr < 4; ++rr) {
                acc[rr][0] = 0.f; acc[rr][1] = 0.f; acc[rr][2] = 0.f; acc[rr][3] = 0.f;
            }

            // 8 kk x (4 P b128 + 4 D b128 + 64 FMA), imm-offset addressing
#pragma unroll
            for (int kk = 0; kk < 8; ++kk) {
                const float4 pv0 = *(const float4*)(Pb + kk * 1024);
                const float4 pv1 = *(const float4*)(Pb + kk * 1024 + 256);
                const float4 pv2 = *(const float4*)(Pb + kk * 1024 + 512);
                const float4 pv3 = *(const float4*)(Pb + kk * 1024 + 768);
#pragma unroll
                for (int rr = 0; rr < 4; ++rr) {
                    const float4 d4 = *(const float4*)(Dw + rr * 144 + kk * 4);
                    acc[rr][0] = fmaf(d4.x, pv0.x, acc[rr][0]);
                    acc[rr][1] = fmaf(d4.x, pv0.y, acc[rr][1]);
                    acc[rr][2] = fmaf(d4.x, pv0.z, acc[rr][2]);
                    acc[rr][3] = fmaf(d4.x, pv0.w, acc[rr][3]);
                    acc[rr][0] = fmaf(d4.y, pv1.x, acc[rr][0]);
                    acc[rr][1] = fmaf(d4.y, pv1.y, acc[rr][1]);
                    acc[rr][2] = fmaf(d4.y, pv1.z, acc[rr][2]);
                    acc[rr][3] = fmaf(d4.y, pv1.w, acc[rr][3]);
                    acc[rr][0] = fmaf(d4.z, pv2.x, acc[rr][0]);
                    acc[rr][1] = fmaf(d4.z, pv2.y, acc[rr][1]);
                    acc[rr][2] = fmaf(d4.z, pv2.z, acc[rr][2]);
                    acc[rr][3] = fmaf(d4.z, pv2.w, acc[rr][3]);
                    acc[rr][0] = fmaf(d4.w, pv3.x, acc[rr][0]);
                    acc[rr][1] = fmaf(d4.w, pv3.y, acc[rr][1]);
                    acc[rr][2] = fmaf(d4.w, pv3.z, acc[rr][2]);
                    acc[rr][3] = fmaf(d4.w, pv3.w, acc[rr][3]);
                }
            }

            // reduce parts (xor 16,32), +e, abs, reduce col-quads (xor 1..8)
#pragma unroll
            for (int rr = 0; rr < 4; ++rr) {
                float a0 = acc[rr][0], a1 = acc[rr][1], a2 = acc[rr][2], a3 = acc[rr][3];
                a0 += __shfl_xor(a0, 16); a0 += __shfl_xor(a0, 32);
                a1 += __shfl_xor(a1, 16); a1 += __shfl_xor(a1, 32);
                a2 += __shfl_xor(a2, 16); a2 += __shfl_xor(a2, 32);
                a3 += __shfl_xor(a3, 16); a3 += __shfl_xor(a3, 32);
                float sv = fabsf(a0 + e4.x) + fabsf(a1 + e4.y)
                         + fabsf(a2 + e4.z) + fabsf(a3 + e4.w);
                sv += __shfl_xor(sv, 1);
                sv += __shfl_xor(sv, 2);
                sv += __shfl_xor(sv, 4);
                sv += __shfl_xor(sv, 8);
                if (lane == rr && rowid[rr] >= 0) out[rowid[rr]] = -sv;
            }
        }

        if (!nhave) break;                     // per-wave exit, no barriers

        // ---- write prefetched d (write-late; same-wave DS ordering
        // guarantees the compute's D reads above already issued) ----
#pragma unroll
        for (int rr = 0; rr < 4; ++rr) {
            rowid[rr] = nrow[rr];
            if (nrow[rr] >= 0)
                *(float2*)(Dwbase + rr * 144 + dwr) = nd[rr];
        }
        base = nbase;
    }
}

extern "C" void kernel_launch(void* const* d_in, const int* in_sizes, int n_in,
                              void* d_out, int out_size, void* d_ws, size_t ws_size,
                              hipStream_t stream) {
    const float* h_head   = (const float*)d_in[0];
    const float* h_tail   = (const float*)d_in[1];
    const int*   rels     = (const int*)d_in[2];
    const float* rel_emb  = (const float*)d_in[3];
    const float* rel_proj = (const float*)d_in[4];
    float* out = (float*)d_out;

    const int B = in_sizes[2];   // 32768

    // ws: cursors[1024] ints | bucket[NUM_RELS*STRIDE] ints
    int* cursors = (int*)d_ws;
    int* bucket  = cursors + 1024;

    hipMemsetAsync(cursors, 0, 1024 * sizeof(int), stream);   // capture-safe
    scatter_kernel<<<(B + 255) / 256, 256, 0, stream>>>(rels, cursors, bucket, B);
    transr_main<<<NUM_RELS, 512, 0, stream>>>(h_head, h_tail, rel_emb, rel_proj,
                                              cursors, bucket, out);
}

// Round 10
// 139.922 us; speedup vs baseline: 2.8292x; 2.8292x over previous
//
#include <hip/hip_runtime.h>

// TransR scoring: out[b] = -sum_j | (h_head[b]-h_tail[b]) . P_r[:,j] + e_r[j] |
// B=32768, NFEATS=128, RFEATS=64, NUM_RELS=1000.
//
// Round-10 = round-7's kernel (best measured: 43 us, VGPR 16, 0 conflicts,
// absmax 0) made 2-phase double-buffered. r8/r9 lesson: no inline-asm
// waitcnt, no guarded register arrays, no fancy fragment loops — the r7
// shape is the only one this compiler compiles without scratch.
//
// Grid 500 x 512 thr; block b owns relations {2b, 2b+1}, LDS = 2 x 32 KB:
//   stage P(r0)->buf0  (+ d(r0) loads overlap)   | barrier (vmcnt drain)
//   stage P(r1)->buf1  issued BEFORE compute(r0) | compute r0 from buf0
//   d(r1) loads                                  | barrier (drain covers buf1)
//   compute r1 from buf1                         |
// The r1 staging hides under r0 compute (T3-minimal 2-phase, no asm).
// 64 KB LDS -> 2 blocks/CU, 16 waves/CU (same occupancy as r7).
//
// Inner loop (r5/r7-validated, absmax 0): lane j owns column j;
// 2 conflict-free imm-offset ds_read_b32 + 8 v_readlane + 8 FMA per q.

#define NFEATS   128
#define RFEATS   64
#define NUM_RELS 1000
#define STRIDE   128   // bucket slots/rel; cnt~Binom(32768,1e-3) mean 32.8 sd 5.7

#define AS_GLOBAL __attribute__((address_space(1)))
#define AS_SHARED __attribute__((address_space(3)))

__global__ void scatter_kernel(const int* __restrict__ rels,
                               int* __restrict__ cursors,
                               int* __restrict__ bucket, int B) {
    int i = blockIdx.x * blockDim.x + threadIdx.x;
    if (i < B) {
        int r = rels[i];
        int s = atomicAdd(&cursors[r], 1);
        if (s < STRIDE) bucket[(r << 7) + s] = i;
    }
}

// ---- macros so both relations compile to the exact r7 code shape ----

#define STAGE(PBUF, RIDX)                                                      \
    {                                                                          \
        const float* Psrc_ = rel_proj + (size_t)(RIDX) * (NFEATS * RFEATS);    \
        _Pragma("unroll")                                                      \
        for (int it_ = 0; it_ < 4; ++it_) {                                    \
            const int off_ = (it_ * 512 + tid) * 4;                            \
            __builtin_amdgcn_global_load_lds(                                  \
                (const AS_GLOBAL void*)(Psrc_ + off_),                         \
                (AS_SHARED void*)((PBUF) + off_), 16, 0, 0);                   \
        }                                                                      \
    }

#define LOADD(CNT, BUK, BASE)                                                  \
    _Pragma("unroll")                                                          \
    for (int rr_ = 0; rr_ < 4; ++rr_) {                                        \
        const int li_ = (BASE) + (w << 2) + rr_;                               \
        rowid[rr_] = (li_ < (CNT)) ? (BUK)[li_] : -1;                          \
        d2[rr_] = make_float2(0.f, 0.f);                                       \
        if (rowid[rr_] >= 0) {                                                 \
            const float2 a_ = *(const float2*)(h_head + (size_t)rowid[rr_] * NFEATS + (lane << 1)); \
            const float2 b_ = *(const float2*)(h_tail + (size_t)rowid[rr_] * NFEATS + (lane << 1)); \
            d2[rr_].x = a_.x - b_.x;                                           \
            d2[rr_].y = a_.y - b_.y;                                           \
        }                                                                      \
    }

#define RL(dst, src, q) dst = __uint_as_float(__builtin_amdgcn_readlane(__float_as_uint(src), q))

#define COMPUTE(CNT, BUK, PBUF, EV)                                            \
    for (int base_ = 0; base_ < (CNT); base_ += 32) {                          \
        if (base_ + (w << 2) < (CNT)) {                                        \
            float acc0 = 0.f, acc1 = 0.f, acc2 = 0.f, acc3 = 0.f;              \
            _Pragma("unroll 8")                                                \
            for (int q = 0; q < 64; ++q) {                                     \
                const float p0 = (PBUF)[(2 * q) * RFEATS + lane];              \
                const float p1 = (PBUF)[(2 * q + 1) * RFEATS + lane];          \
                float dx, dy;                                                  \
                RL(dx, d2[0].x, q); RL(dy, d2[0].y, q);                        \
                acc0 = fmaf(dx, p0, acc0); acc0 = fmaf(dy, p1, acc0);          \
                RL(dx, d2[1].x, q); RL(dy, d2[1].y, q);                        \
                acc1 = fmaf(dx, p0, acc1); acc1 = fmaf(dy, p1, acc1);          \
                RL(dx, d2[2].x, q); RL(dy, d2[2].y, q);                        \
                acc2 = fmaf(dx, p0, acc2); acc2 = fmaf(dy, p1, acc2);          \
                RL(dx, d2[3].x, q); RL(dy, d2[3].y, q);                        \
                acc3 = fmaf(dx, p0, acc3); acc3 = fmaf(dy, p1, acc3);          \
            }                                                                  \
            float s0 = fabsf(acc0 + (EV)), s1 = fabsf(acc1 + (EV));            \
            float s2 = fabsf(acc2 + (EV)), s3 = fabsf(acc3 + (EV));            \
            float sv_[4] = { s0, s1, s2, s3 };                                 \
            _Pragma("unroll")                                                  \
            for (int rr_ = 0; rr_ < 4; ++rr_) {                                \
                float sv = sv_[rr_];                                           \
                sv += __shfl_xor(sv, 1);                                       \
                sv += __shfl_xor(sv, 2);                                       \
                sv += __shfl_xor(sv, 4);                                       \
                sv += __shfl_xor(sv, 8);                                       \
                sv += __shfl_xor(sv, 16);                                      \
                sv += __shfl_xor(sv, 32);                                      \
                if (lane == rr_ && rowid[rr_] >= 0) out[rowid[rr_]] = -sv;     \
            }                                                                  \
        }                                                                      \
        const int nb_ = base_ + 32;                                            \
        if (nb_ < (CNT)) { LOADD((CNT), (BUK), nb_) }                          \
    }

__global__ __launch_bounds__(512, 8) void transr_main(
    const float* __restrict__ h_head,
    const float* __restrict__ h_tail,
    const float* __restrict__ rel_emb,
    const float* __restrict__ rel_proj,
    const int*   __restrict__ cursors,
    const int*   __restrict__ bucket,
    float* __restrict__ out)
{
    __shared__ float Plds[2][NFEATS * RFEATS];   // 2 x 32 KB

    const int tid  = threadIdx.x;                 // 512 = 8 waves
    const int w    = tid >> 6;
    const int lane = tid & 63;

    const int r0 = blockIdx.x << 1;
    const int r1 = r0 + 1;

    // ---- phase 0 prologue: stage P(r0); d(r0) chunk-0 overlaps it ----
    STAGE(&Plds[0][0], r0)

    int cnt0 = cursors[r0]; if (cnt0 > STRIDE) cnt0 = STRIDE;
    int cnt1 = cursors[r1]; if (cnt1 > STRIDE) cnt1 = STRIDE;
    const int* buk0 = bucket + (r0 << 7);
    const int* buk1 = bucket + (r1 << 7);
    const float ev0 = rel_emb[(size_t)r0 * RFEATS + lane];
    const float ev1 = rel_emb[(size_t)r1 * RFEATS + lane];

    int    rowid[4];
    float2 d2[4];
    LOADD(cnt0, buk0, 0)

    __syncthreads();    // buf0 resident (compiler emits vmcnt drain)

    // ---- phase 1: issue P(r1) staging BEFORE computing r0 ----
    STAGE(&Plds[1][0], r1)

    COMPUTE(cnt0, buk0, (&Plds[0][0]), ev0)

    LOADD(cnt1, buk1, 0)

    __syncthreads();    // buf1 resident; stage had all of compute-r0 to land

    // ---- phase 2: compute r1 ----
    COMPUTE(cnt1, buk1, (&Plds[1][0]), ev1)
}

extern "C" void kernel_launch(void* const* d_in, const int* in_sizes, int n_in,
                              void* d_out, int out_size, void* d_ws, size_t ws_size,
                              hipStream_t stream) {
    const float* h_head   = (const float*)d_in[0];
    const float* h_tail   = (const float*)d_in[1];
    const int*   rels     = (const int*)d_in[2];
    const float* rel_emb  = (const float*)d_in[3];
    const float* rel_proj = (const float*)d_in[4];
    float* out = (float*)d_out;

    const int B = in_sizes[2];   // 32768

    // ws: cursors[1024] ints | bucket[NUM_RELS*STRIDE] ints
    int* cursors = (int*)d_ws;
    int* bucket  = cursors + 1024;

    hipMemsetAsync(cursors, 0, 1024 * sizeof(int), stream);   // capture-safe
    scatter_kernel<<<(B + 255) / 256, 256, 0, stream>>>(rels, cursors, bucket, B);
    transr_main<<<NUM_RELS / 2, 512, 0, stream>>>(h_head, h_tail, rel_emb, rel_proj,
                                                  cursors, bucket, out);
}